// Round 6
// baseline (1099.372 us; speedup 1.0000x reference)
//
#include <hip/hip_runtime.h>
#include <cstdint>

// AdaptiveNet: x[16384,1024] -> fc1(4096)+sigmoid -> grouped(512 g of 8)+sigmoid -> fc3(256)
// R6: GEMM1 moves to MX-scaled fp8 MFMA (16x16x128 f8f6f4, unity scales):
// 4x fewer MFMA insts at 2x pipe rate, 2x fewer ds_reads (b128, conflict-free).
// W1 pre-scaled x64 into e4m3, acc*(1/64) in epilogue. gemm3 stays bf16.

#define B_ROWS 16384
#define DIN 1024
#define H1  4096
#define H2  512
#define DOUT 256
#define TILE 128
#define BK 64          // bf16 core (gemm3)
#define BK1 128        // fp8 core (gemm1)
#define INV_W1SCALE 0.015625f   // 1/64
#define SCALE_UNITY 0x7F7F7F7F  // E8M0 = 127 -> x1.0

#define NX4  (B_ROWS * DIN / 4)   // 4194304
#define NW14 (H1 * DIN / 4)       // 1048576
#define NW34 (DOUT * H2 / 4)      // 32768

typedef __bf16 bf16x8 __attribute__((ext_vector_type(8)));
typedef float f32x4 __attribute__((ext_vector_type(4)));
typedef int   i32x4 __attribute__((ext_vector_type(4)));
typedef int   i32x8 __attribute__((ext_vector_type(8)));

__device__ __forceinline__ unsigned short f2bf(float f) {
    union { float f; uint32_t u; } v; v.f = f;
    uint32_t u = v.u;
    u += 0x7FFFu + ((u >> 16) & 1u);   // round-to-nearest-even
    return (unsigned short)(u >> 16);
}

__device__ __forceinline__ float sigmoidf_fast(float x) {
    return 1.0f / (1.0f + __expf(-x));
}

// x -> fp8 (x1), W1 -> fp8 (x64), W3 -> bf16, one launch
__global__ __launch_bounds__(256) void cvt3_kernel(
    const float* __restrict__ x, const float* __restrict__ w1,
    const float* __restrict__ w3, unsigned int* __restrict__ xo,
    unsigned int* __restrict__ w1o, unsigned short* __restrict__ w3o) {
    int i = blockIdx.x * 256 + threadIdx.x;
    if (i < NX4) {
        float4 v = ((const float4*)x)[i];
        unsigned int p = 0;
        p = __builtin_amdgcn_cvt_pk_fp8_f32(v.x, v.y, p, false);
        p = __builtin_amdgcn_cvt_pk_fp8_f32(v.z, v.w, p, true);
        xo[i] = p;
    } else if (i < NX4 + NW14) {
        int j = i - NX4;
        float4 v = ((const float4*)w1)[j];
        unsigned int p = 0;
        p = __builtin_amdgcn_cvt_pk_fp8_f32(v.x * 64.0f, v.y * 64.0f, p, false);
        p = __builtin_amdgcn_cvt_pk_fp8_f32(v.z * 64.0f, v.w * 64.0f, p, true);
        w1o[j] = p;
    } else {
        int j = i - NX4 - NW14;
        float4 v = ((const float4*)w3)[j];
        ushort4 o;
        o.x = f2bf(v.x); o.y = f2bf(v.y); o.z = f2bf(v.z); o.w = f2bf(v.w);
        ((ushort4*)w3o)[j] = o;
    }
}

__device__ __forceinline__ void load_lds16(const void* g, void* l) {
    __builtin_amdgcn_global_load_lds(
        (const __attribute__((address_space(1))) void*)g,
        (__attribute__((address_space(3))) void*)l, 16, 0, 0);
}

// ---------------- MX-fp8 core, BK1=128, tile 128x128 ----------------
// LDS row = 128B = 8 chunks of 16B, chunk c of row r stored at slot (c + (r&7))&7.
// A-frag for 16x16x128: lane(q=l>>4, m=l&15) holds rows m, k = q*32..q*32+31
// = chunks 2q, 2q+1 -> two ds_read_b128 at rotated slots (8 lanes per 4-bank
// group = minimum passes, conflict-free).
__global__ __launch_bounds__(256, 2) void gemm1_fused(
    const unsigned char* __restrict__ Xq,    // [16384,1024] fp8
    const unsigned char* __restrict__ W1q,   // [4096,1024]  fp8 (N,K), x64
    const float* __restrict__ b1,            // [4096]
    const float* __restrict__ W2,            // [512*8] flat; W2[g][s] = W2[gn]
    const float* __restrict__ b2,            // [512]
    unsigned short* __restrict__ X2) {       // [16384,512] bf16
    __shared__ __attribute__((aligned(16))) unsigned char lsA[TILE * BK1];
    __shared__ __attribute__((aligned(16))) unsigned char lsB[TILE * BK1];
    const int tid = threadIdx.x, lane = tid & 63, wave = tid >> 6;
    const int wm = (wave >> 1) * 64, wn = (wave & 1) * 64;

    // XCD-aware decode (R4): xcd owns a 512-col W1 slice (L2-resident)
    const int bid = blockIdx.x;
    const int xcd = bid & 7;
    const int local = bid >> 3;
    const int n0 = (xcd * 4 + (local & 3)) * TILE;
    const int a0 = (local >> 2) * TILE;

    const int q = lane >> 4, m16 = lane & 15;

    // staging: 4 chunks of 1KB per matrix per wave; chunk = 8 rows x 128B
    int gA[4], gB[4], lo[4];
#pragma unroll
    for (int i = 0; i < 4; ++i) {
        const int ch = wave * 4 + i;
        const int r  = ch * 8 + (lane >> 3);
        const int kc = ((lane & 7) - (lane >> 3)) & 7;
        gA[i] = (a0 + r) * DIN + kc * 16;
        gB[i] = (n0 + r) * DIN + kc * 16;
        lo[i] = ch * 1024;
    }
    // fragment read offsets: lane reads chunks 2q, 2q+1 of its row
    const int so0 = ((2 * q     + (m16 & 7)) & 7) * 16;
    const int so1 = ((2 * q + 1 + (m16 & 7)) & 7) * 16;
    int rowA[4], rowB[4];
#pragma unroll
    for (int t = 0; t < 4; ++t) {
        rowA[t] = (wm + t * 16 + m16) * BK1;
        rowB[t] = (wn + t * 16 + m16) * BK1;
    }

    f32x4 acc[4][4];
#pragma unroll
    for (int r = 0; r < 4; ++r)
#pragma unroll
        for (int c = 0; c < 4; ++c) acc[r][c] = (f32x4)0.0f;

    for (int kt = 0; kt < DIN / BK1; ++kt) {
        __syncthreads();
        const int k0 = kt * BK1;
#pragma unroll
        for (int i = 0; i < 4; ++i) {
            load_lds16(Xq + gA[i] + k0, lsA + lo[i]);
            load_lds16(W1q + gB[i] + k0, lsB + lo[i]);
        }
        __syncthreads();
        i32x8 af[4], bfr[4];
#pragma unroll
        for (int t = 0; t < 4; ++t) {
            i32x4 alo = *(const i32x4*)(lsA + rowA[t] + so0);
            i32x4 ahi = *(const i32x4*)(lsA + rowA[t] + so1);
            af[t] = __builtin_shufflevector(alo, ahi, 0, 1, 2, 3, 4, 5, 6, 7);
            i32x4 blo = *(const i32x4*)(lsB + rowB[t] + so0);
            i32x4 bhi = *(const i32x4*)(lsB + rowB[t] + so1);
            bfr[t] = __builtin_shufflevector(blo, bhi, 0, 1, 2, 3, 4, 5, 6, 7);
        }
#pragma unroll
        for (int r = 0; r < 4; ++r)
#pragma unroll
            for (int c = 0; c < 4; ++c)
                acc[r][c] = __builtin_amdgcn_mfma_scale_f32_16x16x128_f8f6f4(
                    af[r], bfr[c], acc[r][c], 0, 0,
                    0, SCALE_UNITY, 0, SCALE_UNITY);
    }

    // Epilogue. C/D layout (shape-determined, m127/m128): col=lane&15, row=q*4+reg.
    // acc is 64x true z1 (W1 pre-scaled).
#pragma unroll
    for (int c = 0; c < 4; ++c) {
        const int gn = n0 + wn + c * 16 + m16;        // h column
        const float w2v = W2[gn];
        const float b1v = b1[gn];
        const int g = gn >> 3;
        const float b2v = b2[g];
#pragma unroll
        for (int r = 0; r < 4; ++r) {
#pragma unroll
            for (int i = 0; i < 4; ++i) {
                const int gm = a0 + wm + r * 16 + q * 4 + i;
                float h = sigmoidf_fast(acc[r][c][i] * INV_W1SCALE + b1v);
                float v = h * w2v;
                v += __shfl_xor(v, 1, 64);
                v += __shfl_xor(v, 2, 64);
                v += __shfl_xor(v, 4, 64);
                if ((lane & 7) == 0)
                    X2[gm * H2 + g] = f2bf(sigmoidf_fast(v + b2v));
            }
        }
    }
}

// ---------------- bf16 core, BK=64 (gemm3) ----------------
template <int K>
__device__ __forceinline__ void gemm_core(const unsigned short* __restrict__ A,
                                          const unsigned short* __restrict__ Bm,
                                          unsigned short* lsA, unsigned short* lsB,
                                          int a_row0, int b_row0,
                                          int lane, int wave, int wm, int wn,
                                          f32x4 acc[4][4]) {
    const int q = lane >> 4, m16 = lane & 15;
    int gA[4], gB[4], lo[4];
#pragma unroll
    for (int i = 0; i < 4; ++i) {
        const int ch = wave * 4 + i;
        const int r  = ch * 8 + (lane >> 3);
        const int kc = ((lane & 7) - (lane >> 3)) & 7;
        gA[i] = (a_row0 + r) * K + kc * 8;
        gB[i] = (b_row0 + r) * K + kc * 8;
        lo[i] = ch * 512;
    }
    int ra[2][4], rb[2][4];
#pragma unroll
    for (int h = 0; h < 2; ++h)
#pragma unroll
        for (int t = 0; t < 4; ++t) {
            const int s = ((h * 4 + q + (m16 & 7)) & 7) * 8;
            ra[h][t] = (wm + t * 16 + m16) * BK + s;
            rb[h][t] = (wn + t * 16 + m16) * BK + s;
        }
    for (int kt = 0; kt < K / BK; ++kt) {
        __syncthreads();
        const int k0 = kt * BK;
#pragma unroll
        for (int i = 0; i < 4; ++i) {
            load_lds16(A + gA[i] + k0, lsA + lo[i]);
            load_lds16(Bm + gB[i] + k0, lsB + lo[i]);
        }
        __syncthreads();
#pragma unroll
        for (int h = 0; h < 2; ++h) {
            bf16x8 af[4], bfr[4];
#pragma unroll
            for (int t = 0; t < 4; ++t) af[t]  = *(const bf16x8*)(lsA + ra[h][t]);
#pragma unroll
            for (int t = 0; t < 4; ++t) bfr[t] = *(const bf16x8*)(lsB + rb[h][t]);
#pragma unroll
            for (int r = 0; r < 4; ++r)
#pragma unroll
                for (int c = 0; c < 4; ++c)
                    acc[r][c] = __builtin_amdgcn_mfma_f32_16x16x32_bf16(
                        af[r], bfr[c], acc[r][c], 0, 0, 0);
        }
    }
}

__global__ __launch_bounds__(256, 2) void gemm3_kernel(
    const unsigned short* __restrict__ X2,   // [16384,512] bf16
    const unsigned short* __restrict__ W3b,  // [256,512] bf16 (N,K)
    const float* __restrict__ b3,            // [256]
    float* __restrict__ Out) {               // [16384,256] f32
    __shared__ __attribute__((aligned(16))) unsigned short lsA[TILE * BK];
    __shared__ __attribute__((aligned(16))) unsigned short lsB[TILE * BK];
    const int tid = threadIdx.x, lane = tid & 63, wave = tid >> 6;
    const int wm = (wave >> 1) * 64, wn = (wave & 1) * 64;
    const int a0 = blockIdx.y * TILE;
    const int n0 = blockIdx.x * TILE;

    f32x4 acc[4][4];
#pragma unroll
    for (int r = 0; r < 4; ++r)
#pragma unroll
        for (int c = 0; c < 4; ++c) acc[r][c] = (f32x4)0.0f;

    gemm_core<H2>(X2, W3b, lsA, lsB, a0, n0, lane, wave, wm, wn, acc);

    const int q = lane >> 4, m16 = lane & 15;
#pragma unroll
    for (int c = 0; c < 4; ++c) {
        const int gn = n0 + wn + c * 16 + m16;
        const float b3v = b3[gn];
#pragma unroll
        for (int r = 0; r < 4; ++r) {
#pragma unroll
            for (int i = 0; i < 4; ++i) {
                const int gm = a0 + wm + r * 16 + q * 4 + i;
                Out[gm * DOUT + gn] = acc[r][c][i] + b3v;
            }
        }
    }
}

extern "C" void kernel_launch(void* const* d_in, const int* in_sizes, int n_in,
                              void* d_out, int out_size, void* d_ws, size_t ws_size,
                              hipStream_t stream) {
    const float* x  = (const float*)d_in[0];
    const float* W1 = (const float*)d_in[1];
    const float* b1 = (const float*)d_in[2];
    const float* W2 = (const float*)d_in[3];
    const float* b2 = (const float*)d_in[4];
    const float* W3 = (const float*)d_in[5];
    const float* b3 = (const float*)d_in[6];
    float* out = (float*)d_out;

    char* ws = (char*)d_ws;
    unsigned char*  x_q   = (unsigned char*)ws;                          // 16,777,216 B
    unsigned char*  w1_q  = (unsigned char*)(ws + 16777216);             //  4,194,304 B
    unsigned short* w3_bf = (unsigned short*)(ws + 16777216 + 4194304);  //    262,144 B
    unsigned short* x2_bf = (unsigned short*)(ws + 16777216 + 4194304 + 262144); // 16,777,216 B

    cvt3_kernel<<<(NX4 + NW14 + NW34) / 256, 256, 0, stream>>>(
        x, W1, W3, (unsigned int*)x_q, (unsigned int*)w1_q, w3_bf);

    // GEMM1 (MX-fp8) + fused layer 2: 1-D grid, XCD-aware decode inside
    gemm1_fused<<<(B_ROWS / TILE) * (H1 / TILE), 256, 0, stream>>>(
        x_q, w1_q, b1, W2, b2, x2_bf);

    // GEMM3 (bf16): grid = (2, 128)
    gemm3_kernel<<<dim3(DOUT / TILE, B_ROWS / TILE), 256, 0, stream>>>(
        x2_bf, w3_bf, b3, out);
}

// Round 7
// 517.174 us; speedup vs baseline: 2.1257x; 2.1257x over previous
//
#include <hip/hip_runtime.h>
#include <cstdint>

// AdaptiveNet: x[16384,1024] -> fc1(4096)+sigmoid -> grouped(512 g of 8)+sigmoid -> fc3(256)
// R7: MX-fp8 16x16x128 GEMM1, de-spilled: __launch_bounds__(256) (no wave clamp),
// operand live-range halved (4 bfr resident, af streamed per row), direct aligned
// i32x8 LDS fragment loads (no shufflevector, unswizzled rows — ds_read 2x passes
// is still under the MFMA pipe time). W1 pre-scaled x64, acc/64 in epilogue.

#define B_ROWS 16384
#define DIN 1024
#define H1  4096
#define H2  512
#define DOUT 256
#define TILE 128
#define BK 64          // bf16 core (gemm3)
#define BK1 128        // fp8 core (gemm1)
#define INV_W1SCALE 0.015625f   // 1/64
#define SCALE_UNITY 0x7F7F7F7F  // E8M0 = 127 -> x1.0

#define NX4  (B_ROWS * DIN / 4)   // 4194304
#define NW14 (H1 * DIN / 4)       // 1048576
#define NW34 (DOUT * H2 / 4)      // 32768

typedef __bf16 bf16x8 __attribute__((ext_vector_type(8)));
typedef float f32x4 __attribute__((ext_vector_type(4)));
typedef int   i32x8 __attribute__((ext_vector_type(8)));

__device__ __forceinline__ unsigned short f2bf(float f) {
    union { float f; uint32_t u; } v; v.f = f;
    uint32_t u = v.u;
    u += 0x7FFFu + ((u >> 16) & 1u);   // round-to-nearest-even
    return (unsigned short)(u >> 16);
}

__device__ __forceinline__ float sigmoidf_fast(float x) {
    return 1.0f / (1.0f + __expf(-x));
}

// x -> fp8 (x1), W1 -> fp8 (x64), W3 -> bf16, one launch
__global__ __launch_bounds__(256) void cvt3_kernel(
    const float* __restrict__ x, const float* __restrict__ w1,
    const float* __restrict__ w3, unsigned int* __restrict__ xo,
    unsigned int* __restrict__ w1o, unsigned short* __restrict__ w3o) {
    int i = blockIdx.x * 256 + threadIdx.x;
    if (i < NX4) {
        float4 v = ((const float4*)x)[i];
        unsigned int p = 0;
        p = __builtin_amdgcn_cvt_pk_fp8_f32(v.x, v.y, p, false);
        p = __builtin_amdgcn_cvt_pk_fp8_f32(v.z, v.w, p, true);
        xo[i] = p;
    } else if (i < NX4 + NW14) {
        int j = i - NX4;
        float4 v = ((const float4*)w1)[j];
        unsigned int p = 0;
        p = __builtin_amdgcn_cvt_pk_fp8_f32(v.x * 64.0f, v.y * 64.0f, p, false);
        p = __builtin_amdgcn_cvt_pk_fp8_f32(v.z * 64.0f, v.w * 64.0f, p, true);
        w1o[j] = p;
    } else {
        int j = i - NX4 - NW14;
        float4 v = ((const float4*)w3)[j];
        ushort4 o;
        o.x = f2bf(v.x); o.y = f2bf(v.y); o.z = f2bf(v.z); o.w = f2bf(v.w);
        ((ushort4*)w3o)[j] = o;
    }
}

__device__ __forceinline__ void load_lds16(const void* g, void* l) {
    __builtin_amdgcn_global_load_lds(
        (const __attribute__((address_space(1))) void*)g,
        (__attribute__((address_space(3))) void*)l, 16, 0, 0);
}

// ---------------- MX-fp8 core, BK1=128, tile 128x128 ----------------
// LDS rows unswizzled: row r at r*128, global k order preserved.
// A-frag for 16x16x128: lane(q=l>>4, m=l&15) holds row m, k = q*32..q*32+31
// -> ONE aligned 32B i32x8 load at row*128 + q*32.
__global__ __launch_bounds__(256) void gemm1_fused(
    const unsigned char* __restrict__ Xq,    // [16384,1024] fp8
    const unsigned char* __restrict__ W1q,   // [4096,1024]  fp8 (N,K), x64
    const float* __restrict__ b1,            // [4096]
    const float* __restrict__ W2,            // [512*8] flat; W2[g][s] = W2[gn]
    const float* __restrict__ b2,            // [512]
    unsigned short* __restrict__ X2) {       // [16384,512] bf16
    __shared__ __attribute__((aligned(32))) unsigned char lsA[TILE * BK1];
    __shared__ __attribute__((aligned(32))) unsigned char lsB[TILE * BK1];
    const int tid = threadIdx.x, lane = tid & 63, wave = tid >> 6;
    const int wm = (wave >> 1) * 64, wn = (wave & 1) * 64;

    // XCD-aware decode (R4): xcd owns a 512-col W1 slice (L2-resident)
    const int bid = blockIdx.x;
    const int xcd = bid & 7;
    const int local = bid >> 3;
    const int n0 = (xcd * 4 + (local & 3)) * TILE;
    const int a0 = (local >> 2) * TILE;

    const int q = lane >> 4, m16 = lane & 15;

    // staging (unswizzled): 4 chunks of 1KB per matrix per wave; chunk = 8 rows x 128B
    // lane l stages row (ch*8 + l>>3), bytes (l&7)*16 .. +16
    int gA[4], gB[4], lo[4];
#pragma unroll
    for (int i = 0; i < 4; ++i) {
        const int ch = wave * 4 + i;
        const int r  = ch * 8 + (lane >> 3);
        gA[i] = (a0 + r) * DIN + (lane & 7) * 16;
        gB[i] = (n0 + r) * DIN + (lane & 7) * 16;
        lo[i] = ch * 1024;
    }
    // fragment byte offsets
    int rowA[4], rowB[4];
#pragma unroll
    for (int t = 0; t < 4; ++t) {
        rowA[t] = (wm + t * 16 + m16) * BK1 + q * 32;
        rowB[t] = (wn + t * 16 + m16) * BK1 + q * 32;
    }

    f32x4 acc[4][4];
#pragma unroll
    for (int r = 0; r < 4; ++r)
#pragma unroll
        for (int c = 0; c < 4; ++c) acc[r][c] = (f32x4)0.0f;

    for (int kt = 0; kt < DIN / BK1; ++kt) {
        __syncthreads();
        const int k0 = kt * BK1;
#pragma unroll
        for (int i = 0; i < 4; ++i) {
            load_lds16(Xq + gA[i] + k0, lsA + lo[i]);
            load_lds16(W1q + gB[i] + k0, lsB + lo[i]);
        }
        __syncthreads();
        // B fragments resident (32 VGPR), A streamed one row at a time (8 VGPR)
        i32x8 bfr[4];
#pragma unroll
        for (int t = 0; t < 4; ++t) bfr[t] = *(const i32x8*)(lsB + rowB[t]);
#pragma unroll
        for (int r = 0; r < 4; ++r) {
            i32x8 af = *(const i32x8*)(lsA + rowA[r]);
#pragma unroll
            for (int c = 0; c < 4; ++c)
                acc[r][c] = __builtin_amdgcn_mfma_scale_f32_16x16x128_f8f6f4(
                    af, bfr[c], acc[r][c], 0, 0,
                    0, SCALE_UNITY, 0, SCALE_UNITY);
        }
    }

    // Epilogue. C/D layout (shape-determined): col=lane&15, row=q*4+reg.
    // acc is 64x true z1 (W1 pre-scaled).
#pragma unroll
    for (int c = 0; c < 4; ++c) {
        const int gn = n0 + wn + c * 16 + m16;        // h column
        const float w2v = W2[gn];
        const float b1v = b1[gn];
        const int g = gn >> 3;
        const float b2v = b2[g];
#pragma unroll
        for (int r = 0; r < 4; ++r) {
#pragma unroll
            for (int i = 0; i < 4; ++i) {
                const int gm = a0 + wm + r * 16 + q * 4 + i;
                float h = sigmoidf_fast(acc[r][c][i] * INV_W1SCALE + b1v);
                float v = h * w2v;
                v += __shfl_xor(v, 1, 64);
                v += __shfl_xor(v, 2, 64);
                v += __shfl_xor(v, 4, 64);
                if ((lane & 7) == 0)
                    X2[gm * H2 + g] = f2bf(sigmoidf_fast(v + b2v));
            }
        }
    }
}

// ---------------- bf16 core, BK=64 (gemm3) ----------------
template <int K>
__device__ __forceinline__ void gemm_core(const unsigned short* __restrict__ A,
                                          const unsigned short* __restrict__ Bm,
                                          unsigned short* lsA, unsigned short* lsB,
                                          int a_row0, int b_row0,
                                          int lane, int wave, int wm, int wn,
                                          f32x4 acc[4][4]) {
    const int q = lane >> 4, m16 = lane & 15;
    int gA[4], gB[4], lo[4];
#pragma unroll
    for (int i = 0; i < 4; ++i) {
        const int ch = wave * 4 + i;
        const int r  = ch * 8 + (lane >> 3);
        const int kc = ((lane & 7) - (lane >> 3)) & 7;
        gA[i] = (a_row0 + r) * K + kc * 8;
        gB[i] = (b_row0 + r) * K + kc * 8;
        lo[i] = ch * 512;
    }
    int ra[2][4], rb[2][4];
#pragma unroll
    for (int h = 0; h < 2; ++h)
#pragma unroll
        for (int t = 0; t < 4; ++t) {
            const int s = ((h * 4 + q + (m16 & 7)) & 7) * 8;
            ra[h][t] = (wm + t * 16 + m16) * BK + s;
            rb[h][t] = (wn + t * 16 + m16) * BK + s;
        }
    for (int kt = 0; kt < K / BK; ++kt) {
        __syncthreads();
        const int k0 = kt * BK;
#pragma unroll
        for (int i = 0; i < 4; ++i) {
            load_lds16(A + gA[i] + k0, lsA + lo[i]);
            load_lds16(Bm + gB[i] + k0, lsB + lo[i]);
        }
        __syncthreads();
#pragma unroll
        for (int h = 0; h < 2; ++h) {
            bf16x8 af[4], bfr[4];
#pragma unroll
            for (int t = 0; t < 4; ++t) af[t]  = *(const bf16x8*)(lsA + ra[h][t]);
#pragma unroll
            for (int t = 0; t < 4; ++t) bfr[t] = *(const bf16x8*)(lsB + rb[h][t]);
#pragma unroll
            for (int r = 0; r < 4; ++r)
#pragma unroll
                for (int c = 0; c < 4; ++c)
                    acc[r][c] = __builtin_amdgcn_mfma_f32_16x16x32_bf16(
                        af[r], bfr[c], acc[r][c], 0, 0, 0);
        }
    }
}

__global__ __launch_bounds__(256, 2) void gemm3_kernel(
    const unsigned short* __restrict__ X2,   // [16384,512] bf16
    const unsigned short* __restrict__ W3b,  // [256,512] bf16 (N,K)
    const float* __restrict__ b3,            // [256]
    float* __restrict__ Out) {               // [16384,256] f32
    __shared__ __attribute__((aligned(16))) unsigned short lsA[TILE * BK];
    __shared__ __attribute__((aligned(16))) unsigned short lsB[TILE * BK];
    const int tid = threadIdx.x, lane = tid & 63, wave = tid >> 6;
    const int wm = (wave >> 1) * 64, wn = (wave & 1) * 64;
    const int a0 = blockIdx.y * TILE;
    const int n0 = blockIdx.x * TILE;

    f32x4 acc[4][4];
#pragma unroll
    for (int r = 0; r < 4; ++r)
#pragma unroll
        for (int c = 0; c < 4; ++c) acc[r][c] = (f32x4)0.0f;

    gemm_core<H2>(X2, W3b, lsA, lsB, a0, n0, lane, wave, wm, wn, acc);

    const int q = lane >> 4, m16 = lane & 15;
#pragma unroll
    for (int c = 0; c < 4; ++c) {
        const int gn = n0 + wn + c * 16 + m16;
        const float b3v = b3[gn];
#pragma unroll
        for (int r = 0; r < 4; ++r) {
#pragma unroll
            for (int i = 0; i < 4; ++i) {
                const int gm = a0 + wm + r * 16 + q * 4 + i;
                Out[gm * DOUT + gn] = acc[r][c][i] + b3v;
            }
        }
    }
}

extern "C" void kernel_launch(void* const* d_in, const int* in_sizes, int n_in,
                              void* d_out, int out_size, void* d_ws, size_t ws_size,
                              hipStream_t stream) {
    const float* x  = (const float*)d_in[0];
    const float* W1 = (const float*)d_in[1];
    const float* b1 = (const float*)d_in[2];
    const float* W2 = (const float*)d_in[3];
    const float* b2 = (const float*)d_in[4];
    const float* W3 = (const float*)d_in[5];
    const float* b3 = (const float*)d_in[6];
    float* out = (float*)d_out;

    char* ws = (char*)d_ws;
    unsigned char*  x_q   = (unsigned char*)ws;                          // 16,777,216 B
    unsigned char*  w1_q  = (unsigned char*)(ws + 16777216);             //  4,194,304 B
    unsigned short* w3_bf = (unsigned short*)(ws + 16777216 + 4194304);  //    262,144 B
    unsigned short* x2_bf = (unsigned short*)(ws + 16777216 + 4194304 + 262144); // 16,777,216 B

    cvt3_kernel<<<(NX4 + NW14 + NW34) / 256, 256, 0, stream>>>(
        x, W1, W3, (unsigned int*)x_q, (unsigned int*)w1_q, w3_bf);

    // GEMM1 (MX-fp8) + fused layer 2: 1-D grid, XCD-aware decode inside
    gemm1_fused<<<(B_ROWS / TILE) * (H1 / TILE), 256, 0, stream>>>(
        x_q, w1_q, b1, W2, b2, x2_bf);

    // GEMM3 (bf16): grid = (2, 128)
    gemm3_kernel<<<dim3(DOUT / TILE, B_ROWS / TILE), 256, 0, stream>>>(
        x2_bf, w3_bf, b3, out);
}

// Round 8
// 346.479 us; speedup vs baseline: 3.1730x; 1.4927x over previous
//
#include <hip/hip_runtime.h>
#include <cstdint>

// AdaptiveNet: x[16384,1024] -> fc1(4096)+sigmoid -> grouped(512 g of 8)+sigmoid -> fc3(256)
// R8: back to non-scaled fp8 (R5 core, verified 195us; MX builtin spills on this
// compiler — R6/R7 post-mortems). Change: 256x128 M-tile, 8 waves/block:
// 2x MFMA per barrier-pair, staged bytes/MFMA 128->96, same 128-reg/wave budget.

#define B_ROWS 16384
#define DIN 1024
#define H1  4096
#define H2  512
#define DOUT 256
#define TILE 128
#define MT1 256        // gemm1 M-tile
#define BK 64          // bf16 core (gemm3)
#define BK1 128        // fp8 core (gemm1)
#define INV_W1SCALE 0.015625f   // 1/64

#define NX4  (B_ROWS * DIN / 4)   // 4194304
#define NW14 (H1 * DIN / 4)       // 1048576
#define NW34 (DOUT * H2 / 4)      // 32768

typedef __bf16 bf16x8 __attribute__((ext_vector_type(8)));
typedef float f32x4 __attribute__((ext_vector_type(4)));

__device__ __forceinline__ unsigned short f2bf(float f) {
    union { float f; uint32_t u; } v; v.f = f;
    uint32_t u = v.u;
    u += 0x7FFFu + ((u >> 16) & 1u);   // round-to-nearest-even
    return (unsigned short)(u >> 16);
}

__device__ __forceinline__ float sigmoidf_fast(float x) {
    return 1.0f / (1.0f + __expf(-x));
}

// x -> fp8 (x1), W1 -> fp8 (x64), W3 -> bf16, one launch
__global__ __launch_bounds__(256) void cvt3_kernel(
    const float* __restrict__ x, const float* __restrict__ w1,
    const float* __restrict__ w3, unsigned int* __restrict__ xo,
    unsigned int* __restrict__ w1o, unsigned short* __restrict__ w3o) {
    int i = blockIdx.x * 256 + threadIdx.x;
    if (i < NX4) {
        float4 v = ((const float4*)x)[i];
        unsigned int p = 0;
        p = __builtin_amdgcn_cvt_pk_fp8_f32(v.x, v.y, p, false);
        p = __builtin_amdgcn_cvt_pk_fp8_f32(v.z, v.w, p, true);
        xo[i] = p;
    } else if (i < NX4 + NW14) {
        int j = i - NX4;
        float4 v = ((const float4*)w1)[j];
        unsigned int p = 0;
        p = __builtin_amdgcn_cvt_pk_fp8_f32(v.x * 64.0f, v.y * 64.0f, p, false);
        p = __builtin_amdgcn_cvt_pk_fp8_f32(v.z * 64.0f, v.w * 64.0f, p, true);
        w1o[j] = p;
    } else {
        int j = i - NX4 - NW14;
        float4 v = ((const float4*)w3)[j];
        ushort4 o;
        o.x = f2bf(v.x); o.y = f2bf(v.y); o.z = f2bf(v.z); o.w = f2bf(v.w);
        ((ushort4*)w3o)[j] = o;
    }
}

__device__ __forceinline__ void load_lds16(const void* g, void* l) {
    __builtin_amdgcn_global_load_lds(
        (const __attribute__((address_space(1))) void*)g,
        (__attribute__((address_space(3))) void*)l, 16, 0, 0);
}

// ---------------- fp8 core, 256x128 tile, BK1=128, 8 waves ----------------
// Geometry identical to R5's verified core; A-tile doubled to 256 rows.
// LDS row = 128B = 8 chunks of 16B, chunk slots rotated by (row&7).
__global__ __launch_bounds__(512) void gemm1_fused(
    const unsigned char* __restrict__ Xq,    // [16384,1024] fp8
    const unsigned char* __restrict__ W1q,   // [4096,1024]  fp8 (N,K), x64
    const float* __restrict__ b1,            // [4096]
    const float* __restrict__ W2,            // [512*8] flat; W2[g][s] = W2[gn]
    const float* __restrict__ b2,            // [512]
    unsigned short* __restrict__ X2) {       // [16384,512] bf16
    __shared__ __attribute__((aligned(16))) unsigned char lsA[MT1 * BK1];   // 32 KB
    __shared__ __attribute__((aligned(16))) unsigned char lsB[TILE * BK1];  // 16 KB
    const int tid = threadIdx.x, lane = tid & 63, wave = tid >> 6;  // wave 0..7
    const int wm = (wave >> 1) * 64, wn = (wave & 1) * 64;          // wm 0..192

    // XCD-aware decode: grid 2048; xcd = bid&7 owns a 512-col W1 slice
    const int bid = blockIdx.x;
    const int xcd = bid & 7;
    const int local = bid >> 3;                 // 0..255
    const int n0 = (xcd * 4 + (local & 3)) * TILE;
    const int a0 = (local >> 2) * MT1;          // 64 M-tiles of 256

    const int q = lane >> 4, m16 = lane & 15;

    // staging: A = 32 chunks (8 waves x 4), B = 16 chunks (8 waves x 2)
    int gA[4], loA[4], gB[2], loB[2];
#pragma unroll
    for (int i = 0; i < 4; ++i) {
        const int ch = wave * 4 + i;            // 0..31
        const int r  = ch * 8 + (lane >> 3);
        const int kc = ((lane & 7) - (lane >> 3)) & 7;
        gA[i]  = (a0 + r) * DIN + kc * 16;
        loA[i] = ch * 1024;
    }
#pragma unroll
    for (int i = 0; i < 2; ++i) {
        const int ch = wave * 2 + i;            // 0..15
        const int r  = ch * 8 + (lane >> 3);
        const int kc = ((lane & 7) - (lane >> 3)) & 7;
        gB[i]  = (n0 + r) * DIN + kc * 16;
        loB[i] = ch * 1024;
    }
    // fragment offsets (R5-verified): rowbase + slotoff
    int rowA[4], rowB[4], so[4];
#pragma unroll
    for (int t = 0; t < 4; ++t) {
        rowA[t] = (wm + t * 16 + m16) * BK1 + (q & 1) * 8;
        rowB[t] = (wn + t * 16 + m16) * BK1 + (q & 1) * 8;
    }
#pragma unroll
    for (int s = 0; s < 4; ++s)
        so[s] = ((s * 2 + (q >> 1) + (m16 & 7)) & 7) * 16;

    f32x4 acc[4][4];
#pragma unroll
    for (int r = 0; r < 4; ++r)
#pragma unroll
        for (int c = 0; c < 4; ++c) acc[r][c] = (f32x4)0.0f;

    for (int kt = 0; kt < DIN / BK1; ++kt) {
        __syncthreads();
        const int k0 = kt * BK1;
#pragma unroll
        for (int i = 0; i < 4; ++i)
            load_lds16(Xq + gA[i] + k0, lsA + loA[i]);
#pragma unroll
        for (int i = 0; i < 2; ++i)
            load_lds16(W1q + gB[i] + k0, lsB + loB[i]);
        __syncthreads();
#pragma unroll
        for (int s = 0; s < 4; ++s) {
            long af[4], bfr[4];
#pragma unroll
            for (int t = 0; t < 4; ++t) af[t]  = *(const long*)(lsA + rowA[t] + so[s]);
#pragma unroll
            for (int t = 0; t < 4; ++t) bfr[t] = *(const long*)(lsB + rowB[t] + so[s]);
#pragma unroll
            for (int r = 0; r < 4; ++r)
#pragma unroll
                for (int c = 0; c < 4; ++c)
                    acc[r][c] = __builtin_amdgcn_mfma_f32_16x16x32_fp8_fp8(
                        af[r], bfr[c], acc[r][c], 0, 0, 0);
        }
    }

    // Epilogue. C/D layout: col = lane&15, row = q*4 + reg. acc is 64x true z1.
#pragma unroll
    for (int c = 0; c < 4; ++c) {
        const int gn = n0 + wn + c * 16 + m16;        // h column
        const float w2v = W2[gn];
        const float b1v = b1[gn];
        const int g = gn >> 3;
        const float b2v = b2[g];
#pragma unroll
        for (int r = 0; r < 4; ++r) {
#pragma unroll
            for (int i = 0; i < 4; ++i) {
                const int gm = a0 + wm + r * 16 + q * 4 + i;
                float h = sigmoidf_fast(acc[r][c][i] * INV_W1SCALE + b1v);
                float v = h * w2v;
                v += __shfl_xor(v, 1, 64);
                v += __shfl_xor(v, 2, 64);
                v += __shfl_xor(v, 4, 64);
                if ((lane & 7) == 0)
                    X2[gm * H2 + g] = f2bf(sigmoidf_fast(v + b2v));
            }
        }
    }
}

// ---------------- bf16 core, BK=64 (gemm3) ----------------
template <int K>
__device__ __forceinline__ void gemm_core(const unsigned short* __restrict__ A,
                                          const unsigned short* __restrict__ Bm,
                                          unsigned short* lsA, unsigned short* lsB,
                                          int a_row0, int b_row0,
                                          int lane, int wave, int wm, int wn,
                                          f32x4 acc[4][4]) {
    const int q = lane >> 4, m16 = lane & 15;
    int gA[4], gB[4], lo[4];
#pragma unroll
    for (int i = 0; i < 4; ++i) {
        const int ch = wave * 4 + i;
        const int r  = ch * 8 + (lane >> 3);
        const int kc = ((lane & 7) - (lane >> 3)) & 7;
        gA[i] = (a_row0 + r) * K + kc * 8;
        gB[i] = (b_row0 + r) * K + kc * 8;
        lo[i] = ch * 512;
    }
    int ra[2][4], rb[2][4];
#pragma unroll
    for (int h = 0; h < 2; ++h)
#pragma unroll
        for (int t = 0; t < 4; ++t) {
            const int s = ((h * 4 + q + (m16 & 7)) & 7) * 8;
            ra[h][t] = (wm + t * 16 + m16) * BK + s;
            rb[h][t] = (wn + t * 16 + m16) * BK + s;
        }
    for (int kt = 0; kt < K / BK; ++kt) {
        __syncthreads();
        const int k0 = kt * BK;
#pragma unroll
        for (int i = 0; i < 4; ++i) {
            load_lds16(A + gA[i] + k0, lsA + lo[i]);
            load_lds16(Bm + gB[i] + k0, lsB + lo[i]);
        }
        __syncthreads();
#pragma unroll
        for (int h = 0; h < 2; ++h) {
            bf16x8 af[4], bfr[4];
#pragma unroll
            for (int t = 0; t < 4; ++t) af[t]  = *(const bf16x8*)(lsA + ra[h][t]);
#pragma unroll
            for (int t = 0; t < 4; ++t) bfr[t] = *(const bf16x8*)(lsB + rb[h][t]);
#pragma unroll
            for (int r = 0; r < 4; ++r)
#pragma unroll
                for (int c = 0; c < 4; ++c)
                    acc[r][c] = __builtin_amdgcn_mfma_f32_16x16x32_bf16(
                        af[r], bfr[c], acc[r][c], 0, 0, 0);
        }
    }
}

__global__ __launch_bounds__(256, 2) void gemm3_kernel(
    const unsigned short* __restrict__ X2,   // [16384,512] bf16
    const unsigned short* __restrict__ W3b,  // [256,512] bf16 (N,K)
    const float* __restrict__ b3,            // [256]
    float* __restrict__ Out) {               // [16384,256] f32
    __shared__ __attribute__((aligned(16))) unsigned short lsA[TILE * BK];
    __shared__ __attribute__((aligned(16))) unsigned short lsB[TILE * BK];
    const int tid = threadIdx.x, lane = tid & 63, wave = tid >> 6;
    const int wm = (wave >> 1) * 64, wn = (wave & 1) * 64;
    const int a0 = blockIdx.y * TILE;
    const int n0 = blockIdx.x * TILE;

    f32x4 acc[4][4];
#pragma unroll
    for (int r = 0; r < 4; ++r)
#pragma unroll
        for (int c = 0; c < 4; ++c) acc[r][c] = (f32x4)0.0f;

    gemm_core<H2>(X2, W3b, lsA, lsB, a0, n0, lane, wave, wm, wn, acc);

    const int q = lane >> 4, m16 = lane & 15;
#pragma unroll
    for (int c = 0; c < 4; ++c) {
        const int gn = n0 + wn + c * 16 + m16;
        const float b3v = b3[gn];
#pragma unroll
        for (int r = 0; r < 4; ++r) {
#pragma unroll
            for (int i = 0; i < 4; ++i) {
                const int gm = a0 + wm + r * 16 + q * 4 + i;
                Out[gm * DOUT + gn] = acc[r][c][i] + b3v;
            }
        }
    }
}

extern "C" void kernel_launch(void* const* d_in, const int* in_sizes, int n_in,
                              void* d_out, int out_size, void* d_ws, size_t ws_size,
                              hipStream_t stream) {
    const float* x  = (const float*)d_in[0];
    const float* W1 = (const float*)d_in[1];
    const float* b1 = (const float*)d_in[2];
    const float* W2 = (const float*)d_in[3];
    const float* b2 = (const float*)d_in[4];
    const float* W3 = (const float*)d_in[5];
    const float* b3 = (const float*)d_in[6];
    float* out = (float*)d_out;

    char* ws = (char*)d_ws;
    unsigned char*  x_q   = (unsigned char*)ws;                          // 16,777,216 B
    unsigned char*  w1_q  = (unsigned char*)(ws + 16777216);             //  4,194,304 B
    unsigned short* w3_bf = (unsigned short*)(ws + 16777216 + 4194304);  //    262,144 B
    unsigned short* x2_bf = (unsigned short*)(ws + 16777216 + 4194304 + 262144); // 16,777,216 B

    cvt3_kernel<<<(NX4 + NW14 + NW34) / 256, 256, 0, stream>>>(
        x, W1, W3, (unsigned int*)x_q, (unsigned int*)w1_q, w3_bf);

    // GEMM1 (fp8, 256x128 tile) + fused layer 2: 1-D grid of 2048
    gemm1_fused<<<(B_ROWS / MT1) * (H1 / TILE), 512, 0, stream>>>(
        x_q, w1_q, b1, W2, b2, x2_bf);

    // GEMM3 (bf16): grid = (2, 128)
    gemm3_kernel<<<dim3(DOUT / TILE, B_ROWS / TILE), 256, 0, stream>>>(
        x2_bf, w3_bf, b3, out);
}

// Round 9
// 306.968 us; speedup vs baseline: 3.5814x; 1.1287x over previous
//
#include <hip/hip_runtime.h>
#include <cstdint>

// AdaptiveNet: x[16384,1024] -> fc1(4096)+sigmoid -> grouped(512 g of 8)+sigmoid -> fc3(256)
// R9: gemm1 = fp8 single-barrier pipelined double-buffer (BK=64, 2x16KB LDS,
// 4 blocks/CU): loads for iter kt+1 issue right after barrier kt, are drained at
// barrier kt+1 -> one full compute phase of latency hiding (AITER principle at
// source level). gemm3 retiled 64x128 (512 blocks, was 256 = 1/CU latency-bound).

#define B_ROWS 16384
#define DIN 1024
#define H1  4096
#define H2  512
#define DOUT 256
#define TILE 128
#define BK 64            // bf16 core (gemm3)
#define BK1 64           // fp8 dbuf core (gemm1)
#define MT3 64           // gemm3 M-tile
#define INV_W1SCALE 0.015625f   // 1/64

#define NX4  (B_ROWS * DIN / 4)   // 4194304
#define NW14 (H1 * DIN / 4)       // 1048576
#define NW34 (DOUT * H2 / 4)      // 32768

typedef __bf16 bf16x8 __attribute__((ext_vector_type(8)));
typedef float f32x4 __attribute__((ext_vector_type(4)));

__device__ __forceinline__ unsigned short f2bf(float f) {
    union { float f; uint32_t u; } v; v.f = f;
    uint32_t u = v.u;
    u += 0x7FFFu + ((u >> 16) & 1u);   // round-to-nearest-even
    return (unsigned short)(u >> 16);
}

__device__ __forceinline__ float sigmoidf_fast(float x) {
    return __builtin_amdgcn_rcpf(1.0f + __expf(-x));  // v_rcp_f32: ~1e-6 rel err, fine vs 2e-2 threshold
}

// x -> fp8 (x1), W1 -> fp8 (x64), W3 -> bf16, one launch
__global__ __launch_bounds__(256) void cvt3_kernel(
    const float* __restrict__ x, const float* __restrict__ w1,
    const float* __restrict__ w3, unsigned int* __restrict__ xo,
    unsigned int* __restrict__ w1o, unsigned short* __restrict__ w3o) {
    int i = blockIdx.x * 256 + threadIdx.x;
    if (i < NX4) {
        float4 v = ((const float4*)x)[i];
        unsigned int p = 0;
        p = __builtin_amdgcn_cvt_pk_fp8_f32(v.x, v.y, p, false);
        p = __builtin_amdgcn_cvt_pk_fp8_f32(v.z, v.w, p, true);
        xo[i] = p;
    } else if (i < NX4 + NW14) {
        int j = i - NX4;
        float4 v = ((const float4*)w1)[j];
        unsigned int p = 0;
        p = __builtin_amdgcn_cvt_pk_fp8_f32(v.x * 64.0f, v.y * 64.0f, p, false);
        p = __builtin_amdgcn_cvt_pk_fp8_f32(v.z * 64.0f, v.w * 64.0f, p, true);
        w1o[j] = p;
    } else {
        int j = i - NX4 - NW14;
        float4 v = ((const float4*)w3)[j];
        ushort4 o;
        o.x = f2bf(v.x); o.y = f2bf(v.y); o.z = f2bf(v.z); o.w = f2bf(v.w);
        ((ushort4*)w3o)[j] = o;
    }
}

__device__ __forceinline__ void load_lds16(const void* g, void* l) {
    __builtin_amdgcn_global_load_lds(
        (const __attribute__((address_space(1))) void*)g,
        (__attribute__((address_space(3))) void*)l, 16, 0, 0);
}

// ---------------- fp8 pipelined dbuf core, BK1=64, tile 128x128 ----------------
// LDS row = 64B = 4 chunks of 16B; chunk c of row r at slot (c + (r&3))&3
// (R2-verified byte geometry). Fragment b64 read: chunk c = s*2 + (q>>1),
// byte = row*64 + slot*16 + (q&1)*8.
__global__ __launch_bounds__(256, 2) void gemm1_fused(
    const unsigned char* __restrict__ Xq,    // [16384,1024] fp8
    const unsigned char* __restrict__ W1q,   // [4096,1024]  fp8 (N,K), x64
    const float* __restrict__ b1,            // [4096]
    const float* __restrict__ W2,            // [512*8] flat; W2[g][s] = W2[gn]
    const float* __restrict__ b2,            // [512]
    unsigned short* __restrict__ X2) {       // [16384,512] bf16
    __shared__ __attribute__((aligned(16))) unsigned char lsA[2][TILE * BK1]; // 2x8KB
    __shared__ __attribute__((aligned(16))) unsigned char lsB[2][TILE * BK1]; // 2x8KB
    const int tid = threadIdx.x, lane = tid & 63, wave = tid >> 6;
    const int wm = (wave >> 1) * 64, wn = (wave & 1) * 64;

    // XCD-aware decode (R4): xcd owns a 512-col W1 slice (L2-resident)
    const int bid = blockIdx.x;
    const int xcd = bid & 7;
    const int local = bid >> 3;
    const int n0 = (xcd * 4 + (local & 3)) * TILE;
    const int a0 = (local >> 2) * TILE;

    const int q = lane >> 4, m16 = lane & 15;

    // staging: A = 8 chunks of 1KB (128 rows x 64B), wave stages 2; same for B.
    // lane stages row (ch*16 + l>>2), k-chunk kc = ((l&3)-(l>>2))&3 (swizzle).
    int gA[2], gB[2], lo[2];
#pragma unroll
    for (int i = 0; i < 2; ++i) {
        const int ch = wave * 2 + i;            // 0..7
        const int r  = ch * 16 + (lane >> 2);
        const int kc = ((lane & 3) - (lane >> 2)) & 3;
        gA[i] = (a0 + r) * DIN + kc * 16;
        gB[i] = (n0 + r) * DIN + kc * 16;
        lo[i] = ch * 1024;
    }
    // fragment offsets: rowbase + per-s slot offset
    int rowA[4], rowB[4], so[2];
#pragma unroll
    for (int t = 0; t < 4; ++t) {
        rowA[t] = (wm + t * 16 + m16) * BK1;
        rowB[t] = (wn + t * 16 + m16) * BK1;
    }
#pragma unroll
    for (int s = 0; s < 2; ++s)
        so[s] = ((s * 2 + (q >> 1) + (m16 & 3)) & 3) * 16 + (q & 1) * 8;

    f32x4 acc[4][4];
#pragma unroll
    for (int r = 0; r < 4; ++r)
#pragma unroll
        for (int c = 0; c < 4; ++c) acc[r][c] = (f32x4)0.0f;

    // prologue: stage kt=0 into buffer 0
#pragma unroll
    for (int i = 0; i < 2; ++i) {
        load_lds16(Xq + gA[i], lsA[0] + lo[i]);
        load_lds16(W1q + gB[i], lsB[0] + lo[i]);
    }

    // pipelined loop: barrier drains buf[kt] loads (issued one compute-phase ago)
#pragma unroll 2
    for (int kt = 0; kt < DIN / BK1; ++kt) {
        const int p = kt & 1;
        __syncthreads();
        if (kt + 1 < DIN / BK1) {
            const int k1 = (kt + 1) * BK1;
#pragma unroll
            for (int i = 0; i < 2; ++i) {
                load_lds16(Xq + gA[i] + k1, lsA[p ^ 1] + lo[i]);
                load_lds16(W1q + gB[i] + k1, lsB[p ^ 1] + lo[i]);
            }
        }
#pragma unroll
        for (int s = 0; s < 2; ++s) {
            long af[4], bfr[4];
#pragma unroll
            for (int t = 0; t < 4; ++t) af[t]  = *(const long*)(lsA[p] + rowA[t] + so[s]);
#pragma unroll
            for (int t = 0; t < 4; ++t) bfr[t] = *(const long*)(lsB[p] + rowB[t] + so[s]);
#pragma unroll
            for (int r = 0; r < 4; ++r)
#pragma unroll
                for (int c = 0; c < 4; ++c)
                    acc[r][c] = __builtin_amdgcn_mfma_f32_16x16x32_fp8_fp8(
                        af[r], bfr[c], acc[r][c], 0, 0, 0);
        }
    }

    // Epilogue. C/D layout: col = lane&15, row = q*4 + reg. acc is 64x true z1.
#pragma unroll
    for (int c = 0; c < 4; ++c) {
        const int gn = n0 + wn + c * 16 + m16;        // h column
        const float w2v = W2[gn];
        const float b1v = b1[gn];
        const int g = gn >> 3;
        const float b2v = b2[g];
#pragma unroll
        for (int r = 0; r < 4; ++r) {
#pragma unroll
            for (int i = 0; i < 4; ++i) {
                const int gm = a0 + wm + r * 16 + q * 4 + i;
                float h = sigmoidf_fast(acc[r][c][i] * INV_W1SCALE + b1v);
                float v = h * w2v;
                v += __shfl_xor(v, 1, 64);
                v += __shfl_xor(v, 2, 64);
                v += __shfl_xor(v, 4, 64);
                if ((lane & 7) == 0)
                    X2[gm * H2 + g] = f2bf(sigmoidf_fast(v + b2v));
            }
        }
    }
}

// ---------------- bf16 gemm3: 64x128 tile, grid 512 (2 blocks/CU) ----------------
// A-tile 64x64 bf16 (8KB, 8 chunks), B-tile 128x64 (16KB, 16 chunks).
// Wave w owns rows 0..63 (4 r-tiles), cols w*32..w*32+31 (2 c-tiles).
__global__ __launch_bounds__(256, 2) void gemm3_kernel(
    const unsigned short* __restrict__ X2,   // [16384,512] bf16
    const unsigned short* __restrict__ W3b,  // [256,512] bf16 (N,K)
    const float* __restrict__ b3,            // [256]
    float* __restrict__ Out) {               // [16384,256] f32
    __shared__ __attribute__((aligned(16))) unsigned short lsA[MT3 * BK];
    __shared__ __attribute__((aligned(16))) unsigned short lsB[TILE * BK];
    const int tid = threadIdx.x, lane = tid & 63, wave = tid >> 6;
    const int wn = wave * 32;
    const int a0 = blockIdx.y * MT3;
    const int n0 = blockIdx.x * TILE;
    const int q = lane >> 4, m16 = lane & 15;

    // staging (R3-verified geometry): chunk = 8 rows x 128B; lane stages row
    // ch*8 + l>>3, k-chunk kc = ((l&7)-(l>>3))&7
    int gA[2], loA[2], gB[4], loB[4];
#pragma unroll
    for (int i = 0; i < 2; ++i) {
        const int ch = wave * 2 + i;            // 0..7 (A: 8 chunks)
        const int r  = ch * 8 + (lane >> 3);
        const int kc = ((lane & 7) - (lane >> 3)) & 7;
        gA[i]  = (a0 + r) * H2 + kc * 8;
        loA[i] = ch * 512;
    }
#pragma unroll
    for (int i = 0; i < 4; ++i) {
        const int ch = wave * 4 + i;            // 0..15 (B: 16 chunks)
        const int r  = ch * 8 + (lane >> 3);
        const int kc = ((lane & 7) - (lane >> 3)) & 7;
        gB[i]  = (n0 + r) * H2 + kc * 8;
        loB[i] = ch * 512;
    }
    int ra[2][4], rb[2][2];
#pragma unroll
    for (int h = 0; h < 2; ++h) {
        const int s = ((h * 4 + q + (m16 & 7)) & 7) * 8;
#pragma unroll
        for (int t = 0; t < 4; ++t) ra[h][t] = (t * 16 + m16) * BK + s;
#pragma unroll
        for (int c = 0; c < 2; ++c) rb[h][c] = (wn + c * 16 + m16) * BK + s;
    }

    f32x4 acc[4][2];
#pragma unroll
    for (int r = 0; r < 4; ++r)
#pragma unroll
        for (int c = 0; c < 2; ++c) acc[r][c] = (f32x4)0.0f;

    for (int kt = 0; kt < H2 / BK; ++kt) {
        __syncthreads();
        const int k0 = kt * BK;
#pragma unroll
        for (int i = 0; i < 2; ++i)
            load_lds16(X2 + gA[i] + k0, lsA + loA[i]);
#pragma unroll
        for (int i = 0; i < 4; ++i)
            load_lds16(W3b + gB[i] + k0, lsB + loB[i]);
        __syncthreads();
#pragma unroll
        for (int h = 0; h < 2; ++h) {
            bf16x8 af[4], bfr[2];
#pragma unroll
            for (int t = 0; t < 4; ++t) af[t]  = *(const bf16x8*)(lsA + ra[h][t]);
#pragma unroll
            for (int c = 0; c < 2; ++c) bfr[c] = *(const bf16x8*)(lsB + rb[h][c]);
#pragma unroll
            for (int r = 0; r < 4; ++r)
#pragma unroll
                for (int c = 0; c < 2; ++c)
                    acc[r][c] = __builtin_amdgcn_mfma_f32_16x16x32_bf16(
                        af[r], bfr[c], acc[r][c], 0, 0, 0);
        }
    }

#pragma unroll
    for (int c = 0; c < 2; ++c) {
        const int gn = n0 + wn + c * 16 + m16;
        const float b3v = b3[gn];
#pragma unroll
        for (int r = 0; r < 4; ++r) {
#pragma unroll
            for (int i = 0; i < 4; ++i) {
                const int gm = a0 + r * 16 + q * 4 + i;
                Out[gm * DOUT + gn] = acc[r][c][i] + b3v;
            }
        }
    }
}

extern "C" void kernel_launch(void* const* d_in, const int* in_sizes, int n_in,
                              void* d_out, int out_size, void* d_ws, size_t ws_size,
                              hipStream_t stream) {
    const float* x  = (const float*)d_in[0];
    const float* W1 = (const float*)d_in[1];
    const float* b1 = (const float*)d_in[2];
    const float* W2 = (const float*)d_in[3];
    const float* b2 = (const float*)d_in[4];
    const float* W3 = (const float*)d_in[5];
    const float* b3 = (const float*)d_in[6];
    float* out = (float*)d_out;

    char* ws = (char*)d_ws;
    unsigned char*  x_q   = (unsigned char*)ws;                          // 16,777,216 B
    unsigned char*  w1_q  = (unsigned char*)(ws + 16777216);             //  4,194,304 B
    unsigned short* w3_bf = (unsigned short*)(ws + 16777216 + 4194304);  //    262,144 B
    unsigned short* x2_bf = (unsigned short*)(ws + 16777216 + 4194304 + 262144); // 16,777,216 B

    cvt3_kernel<<<(NX4 + NW14 + NW34) / 256, 256, 0, stream>>>(
        x, W1, W3, (unsigned int*)x_q, (unsigned int*)w1_q, w3_bf);

    // GEMM1 (fp8, pipelined dbuf) + fused layer 2: 1-D grid 4096, XCD decode inside
    gemm1_fused<<<(B_ROWS / TILE) * (H1 / TILE), 256, 0, stream>>>(
        x_q, w1_q, b1, W2, b2, x2_bf);

    // GEMM3 (bf16, 64x128): grid = (2, 256) = 512 blocks
    gemm3_kernel<<<dim3(DOUT / TILE, B_ROWS / MT3), 256, 0, stream>>>(
        x2_bf, w3_bf, b3, out);
}

// Round 10
// 282.099 us; speedup vs baseline: 3.8971x; 1.0882x over previous
//
#include <hip/hip_runtime.h>
#include <cstdint>

// AdaptiveNet: x[16384,1024] -> fc1(4096)+sigmoid -> grouped(512 g of 8)+sigmoid -> fc3(256)
// R10: fp8 gemm1 (dbuf, BK=64) with PERMUTED fp8 global layout: cvt stores each
// 64B k-block so a lane's MFMA fragment (k=s*32+q*8, s=0,1) is 16B contiguous at
// byte ((q+(row>>1))&3)*16 + s*8 -> ONE conflict-free ds_read_b128 per fragment
// (was 4-way-conflicted ds_read_b64 x2 = the ~82us/CU LDS serialization wall).
// gemm3 reverted to R5's 128x128 (R9 retile regressed the tail ~30us).

#define B_ROWS 16384
#define DIN 1024
#define H1  4096
#define H2  512
#define DOUT 256
#define TILE 128
#define BK 64            // bf16 core (gemm3)
#define BK1 64           // fp8 dbuf core (gemm1)
#define INV_W1SCALE 0.015625f   // 1/64

#define NXP  (B_ROWS * DIN / 8)   // 2097152  x 8-byte pieces
#define NW1P (H1 * DIN / 8)       // 524288   W1 8-byte pieces
#define NW34 (DOUT * H2 / 4)      // 32768    W3 float4 groups

typedef __bf16 bf16x8 __attribute__((ext_vector_type(8)));
typedef float f32x4 __attribute__((ext_vector_type(4)));
typedef long i64x2 __attribute__((ext_vector_type(2)));

__device__ __forceinline__ unsigned short f2bf(float f) {
    union { float f; uint32_t u; } v; v.f = f;
    uint32_t u = v.u;
    u += 0x7FFFu + ((u >> 16) & 1u);   // round-to-nearest-even
    return (unsigned short)(u >> 16);
}

__device__ __forceinline__ float sigmoidf_fast(float x) {
    return __builtin_amdgcn_rcpf(1.0f + __expf(-x));
}

__device__ __forceinline__ unsigned long long pack8_fp8(float4 v0, float4 v1, float sc) {
    unsigned int p0 = 0, p1 = 0;
    p0 = __builtin_amdgcn_cvt_pk_fp8_f32(v0.x * sc, v0.y * sc, p0, false);
    p0 = __builtin_amdgcn_cvt_pk_fp8_f32(v0.z * sc, v0.w * sc, p0, true);
    p1 = __builtin_amdgcn_cvt_pk_fp8_f32(v1.x * sc, v1.y * sc, p1, false);
    p1 = __builtin_amdgcn_cvt_pk_fp8_f32(v1.z * sc, v1.w * sc, p1, true);
    return (unsigned long long)p0 | ((unsigned long long)p1 << 32);
}

// x -> fp8 permuted (x1), W1 -> fp8 permuted (x64), W3 -> bf16.
// fp8 permutation, per row ri and 64B k-block kb: 8B piece j (q=j&3, s=j>>2)
// stored at byte ((q + (ri>>1)) & 3)*16 + s*8.
__global__ __launch_bounds__(256) void cvt3_kernel(
    const float* __restrict__ x, const float* __restrict__ w1,
    const float* __restrict__ w3, unsigned char* __restrict__ xo,
    unsigned char* __restrict__ w1o, unsigned short* __restrict__ w3o) {
    int i = blockIdx.x * 256 + threadIdx.x;
    if (i < NXP + NW1P) {
        const float* src; unsigned char* dst; int j0; float sc;
        if (i < NXP) { src = x;  dst = xo;  j0 = i;        sc = 1.0f; }
        else         { src = w1; dst = w1o; j0 = i - NXP;  sc = 64.0f; }
        const int ri = j0 >> 7, rem = j0 & 127, kb = rem >> 3, j = rem & 7;
        const float4* s4 = (const float4*)(src + ri * DIN + kb * 64 + j * 8);
        float4 v0 = s4[0], v1 = s4[1];
        const int q = j & 3, s = j >> 2;
        const int pos = ((q + (ri >> 1)) & 3) * 16 + s * 8;
        *(unsigned long long*)(dst + ri * DIN + kb * 64 + pos) = pack8_fp8(v0, v1, sc);
    } else {
        int j = i - NXP - NW1P;
        float4 v = ((const float4*)w3)[j];
        ushort4 o;
        o.x = f2bf(v.x); o.y = f2bf(v.y); o.z = f2bf(v.z); o.w = f2bf(v.w);
        ((ushort4*)w3o)[j] = o;
    }
}

__device__ __forceinline__ void load_lds16(const void* g, void* l) {
    __builtin_amdgcn_global_load_lds(
        (const __attribute__((address_space(1))) void*)g,
        (__attribute__((address_space(3))) void*)l, 16, 0, 0);
}

// ---------------- fp8 pipelined dbuf core, BK1=64, tile 128x128 ----------------
// LDS = linear copy of the permuted global layout (row-major, 64B rows).
// Fragment read: one ds_read_b128 at row*64 + ((q+(row>>1))&3)*16 ->
// (s=0 long, s=1 long); rotation spreads the wave over all 8 4-bank groups
// at 8 passes = minimum (conflict-free).
__global__ __launch_bounds__(256, 2) void gemm1_fused(
    const unsigned char* __restrict__ Xq,    // [16384,1024] fp8 permuted
    const unsigned char* __restrict__ W1q,   // [4096,1024]  fp8 permuted, x64
    const float* __restrict__ b1,            // [4096]
    const float* __restrict__ W2,            // [512*8] flat; W2[g][s] = W2[gn]
    const float* __restrict__ b2,            // [512]
    unsigned short* __restrict__ X2) {       // [16384,512] bf16
    __shared__ __attribute__((aligned(16))) unsigned char lsA[2][TILE * BK1]; // 2x8KB
    __shared__ __attribute__((aligned(16))) unsigned char lsB[2][TILE * BK1]; // 2x8KB
    const int tid = threadIdx.x, lane = tid & 63, wave = tid >> 6;
    const int wm = (wave >> 1) * 64, wn = (wave & 1) * 64;

    // XCD-aware decode (R4): xcd owns a 512-col W1 slice (L2-resident)
    const int bid = blockIdx.x;
    const int xcd = bid & 7;
    const int local = bid >> 3;
    const int n0 = (xcd * 4 + (local & 3)) * TILE;
    const int a0 = (local >> 2) * TILE;

    const int q = lane >> 4, m16 = lane & 15;

    // staging: 8 chunks of 1KB per matrix (chunk = 16 rows x 64B); wave stages 2.
    // Pure linear copy — permutation already applied in global memory.
    int gA[2], gB[2], lo[2];
#pragma unroll
    for (int i = 0; i < 2; ++i) {
        const int ch = wave * 2 + i;            // 0..7
        const int r  = ch * 16 + (lane >> 2);
        gA[i] = (a0 + r) * DIN + (lane & 3) * 16;
        gB[i] = (n0 + r) * DIN + (lane & 3) * 16;
        lo[i] = ch * 1024;
    }
    // fragment byte offsets: one b128 per row
    int fa[4], fb[4];
#pragma unroll
    for (int t = 0; t < 4; ++t) {
        const int ra = wm + t * 16 + m16;
        const int rb = wn + t * 16 + m16;
        fa[t] = ra * BK1 + ((q + (ra >> 1)) & 3) * 16;
        fb[t] = rb * BK1 + ((q + (rb >> 1)) & 3) * 16;
    }

    f32x4 acc[4][4];
#pragma unroll
    for (int r = 0; r < 4; ++r)
#pragma unroll
        for (int c = 0; c < 4; ++c) acc[r][c] = (f32x4)0.0f;

    // prologue: stage kt=0 into buffer 0
#pragma unroll
    for (int i = 0; i < 2; ++i) {
        load_lds16(Xq + gA[i], lsA[0] + lo[i]);
        load_lds16(W1q + gB[i], lsB[0] + lo[i]);
    }

    // pipelined loop: barrier drains buf[kt] loads (issued one compute-phase ago)
#pragma unroll 2
    for (int kt = 0; kt < DIN / BK1; ++kt) {
        const int p = kt & 1;
        __syncthreads();
        if (kt + 1 < DIN / BK1) {
            const int k1 = (kt + 1) * BK1;
#pragma unroll
            for (int i = 0; i < 2; ++i) {
                load_lds16(Xq + gA[i] + k1, lsA[p ^ 1] + lo[i]);
                load_lds16(W1q + gB[i] + k1, lsB[p ^ 1] + lo[i]);
            }
        }
        i64x2 va[4], vb[4];
#pragma unroll
        for (int t = 0; t < 4; ++t) va[t] = *(const i64x2*)(lsA[p] + fa[t]);
#pragma unroll
        for (int t = 0; t < 4; ++t) vb[t] = *(const i64x2*)(lsB[p] + fb[t]);
#pragma unroll
        for (int s = 0; s < 2; ++s)
#pragma unroll
            for (int r = 0; r < 4; ++r)
#pragma unroll
                for (int c = 0; c < 4; ++c)
                    acc[r][c] = __builtin_amdgcn_mfma_f32_16x16x32_fp8_fp8(
                        va[r][s], vb[c][s], acc[r][c], 0, 0, 0);
    }

    // Epilogue. C/D layout: col = lane&15, row = q*4 + reg. acc is 64x true z1.
#pragma unroll
    for (int c = 0; c < 4; ++c) {
        const int gn = n0 + wn + c * 16 + m16;        // h column
        const float w2v = W2[gn];
        const float b1v = b1[gn];
        const int g = gn >> 3;
        const float b2v = b2[g];
#pragma unroll
        for (int r = 0; r < 4; ++r) {
#pragma unroll
            for (int i = 0; i < 4; ++i) {
                const int gm = a0 + wm + r * 16 + q * 4 + i;
                float h = sigmoidf_fast(acc[r][c][i] * INV_W1SCALE + b1v);
                float v = h * w2v;
                v += __shfl_xor(v, 1, 64);
                v += __shfl_xor(v, 2, 64);
                v += __shfl_xor(v, 4, 64);
                if ((lane & 7) == 0)
                    X2[gm * H2 + g] = f2bf(sigmoidf_fast(v + b2v));
            }
        }
    }
}

// ---------------- bf16 core, BK=64 (gemm3, R5-verified) ----------------
template <int K>
__device__ __forceinline__ void gemm_core(const unsigned short* __restrict__ A,
                                          const unsigned short* __restrict__ Bm,
                                          unsigned short* lsA, unsigned short* lsB,
                                          int a_row0, int b_row0,
                                          int lane, int wave, int wm, int wn,
                                          f32x4 acc[4][4]) {
    const int q = lane >> 4, m16 = lane & 15;
    int gA[4], gB[4], lo[4];
#pragma unroll
    for (int i = 0; i < 4; ++i) {
        const int ch = wave * 4 + i;
        const int r  = ch * 8 + (lane >> 3);
        const int kc = ((lane & 7) - (lane >> 3)) & 7;
        gA[i] = (a_row0 + r) * K + kc * 8;
        gB[i] = (b_row0 + r) * K + kc * 8;
        lo[i] = ch * 512;
    }
    int ra[2][4], rb[2][4];
#pragma unroll
    for (int h = 0; h < 2; ++h)
#pragma unroll
        for (int t = 0; t < 4; ++t) {
            const int s = ((h * 4 + q + (m16 & 7)) & 7) * 8;
            ra[h][t] = (wm + t * 16 + m16) * BK + s;
            rb[h][t] = (wn + t * 16 + m16) * BK + s;
        }
    for (int kt = 0; kt < K / BK; ++kt) {
        __syncthreads();
        const int k0 = kt * BK;
#pragma unroll
        for (int i = 0; i < 4; ++i) {
            load_lds16(A + gA[i] + k0, lsA + lo[i]);
            load_lds16(Bm + gB[i] + k0, lsB + lo[i]);
        }
        __syncthreads();
#pragma unroll
        for (int h = 0; h < 2; ++h) {
            bf16x8 af[4], bfr[4];
#pragma unroll
            for (int t = 0; t < 4; ++t) af[t]  = *(const bf16x8*)(lsA + ra[h][t]);
#pragma unroll
            for (int t = 0; t < 4; ++t) bfr[t] = *(const bf16x8*)(lsB + rb[h][t]);
#pragma unroll
            for (int r = 0; r < 4; ++r)
#pragma unroll
                for (int c = 0; c < 4; ++c)
                    acc[r][c] = __builtin_amdgcn_mfma_f32_16x16x32_bf16(
                        af[r], bfr[c], acc[r][c], 0, 0, 0);
        }
    }
}

__global__ __launch_bounds__(256, 2) void gemm3_kernel(
    const unsigned short* __restrict__ X2,   // [16384,512] bf16
    const unsigned short* __restrict__ W3b,  // [256,512] bf16 (N,K)
    const float* __restrict__ b3,            // [256]
    float* __restrict__ Out) {               // [16384,256] f32
    __shared__ __attribute__((aligned(16))) unsigned short lsA[TILE * BK];
    __shared__ __attribute__((aligned(16))) unsigned short lsB[TILE * BK];
    const int tid = threadIdx.x, lane = tid & 63, wave = tid >> 6;
    const int wm = (wave >> 1) * 64, wn = (wave & 1) * 64;
    const int a0 = blockIdx.y * TILE;
    const int n0 = blockIdx.x * TILE;

    f32x4 acc[4][4];
#pragma unroll
    for (int r = 0; r < 4; ++r)
#pragma unroll
        for (int c = 0; c < 4; ++c) acc[r][c] = (f32x4)0.0f;

    gemm_core<H2>(X2, W3b, lsA, lsB, a0, n0, lane, wave, wm, wn, acc);

    const int q = lane >> 4, m16 = lane & 15;
#pragma unroll
    for (int c = 0; c < 4; ++c) {
        const int gn = n0 + wn + c * 16 + m16;
        const float b3v = b3[gn];
#pragma unroll
        for (int r = 0; r < 4; ++r) {
#pragma unroll
            for (int i = 0; i < 4; ++i) {
                const int gm = a0 + wm + r * 16 + q * 4 + i;
                Out[gm * DOUT + gn] = acc[r][c][i] + b3v;
            }
        }
    }
}

extern "C" void kernel_launch(void* const* d_in, const int* in_sizes, int n_in,
                              void* d_out, int out_size, void* d_ws, size_t ws_size,
                              hipStream_t stream) {
    const float* x  = (const float*)d_in[0];
    const float* W1 = (const float*)d_in[1];
    const float* b1 = (const float*)d_in[2];
    const float* W2 = (const float*)d_in[3];
    const float* b2 = (const float*)d_in[4];
    const float* W3 = (const float*)d_in[5];
    const float* b3 = (const float*)d_in[6];
    float* out = (float*)d_out;

    char* ws = (char*)d_ws;
    unsigned char*  x_q   = (unsigned char*)ws;                          // 16,777,216 B
    unsigned char*  w1_q  = (unsigned char*)(ws + 16777216);             //  4,194,304 B
    unsigned short* w3_bf = (unsigned short*)(ws + 16777216 + 4194304);  //    262,144 B
    unsigned short* x2_bf = (unsigned short*)(ws + 16777216 + 4194304 + 262144); // 16,777,216 B

    // cvt: fp8 permute x & W1, bf16 W3. grid = (NXP+NW1P+NW34)/256 = 10368
    cvt3_kernel<<<(NXP + NW1P + NW34) / 256, 256, 0, stream>>>(
        x, W1, W3, x_q, w1_q, w3_bf);

    // GEMM1 (fp8 dbuf, permuted layout) + fused layer 2: 1-D grid 4096
    gemm1_fused<<<(B_ROWS / TILE) * (H1 / TILE), 256, 0, stream>>>(
        x_q, w1_q, b1, W2, b2, x2_bf);

    // GEMM3 (bf16): grid = (2, 128)
    gemm3_kernel<<<dim3(DOUT / TILE, B_ROWS / TILE), 256, 0, stream>>>(
        x2_bf, w3_bf, b3, out);
}